// Round 10
// baseline (6837.715 us; speedup 1.0000x reference)
//
#include <hip/hip_runtime.h>
#include <math.h>

#define HID   256
#define GATES 1024   // 4*HID
#define BATCH 64
#define SEQ   2048

// ---------------------------------------------------------------------------
// Standalone GEMM (prologue only)
// ---------------------------------------------------------------------------
#define BM 128
#define BN 128
#define BK 16
#define LDP 132

__global__ __launch_bounds__(256, 2)
void xg_gemm(const float* __restrict__ A, const float* __restrict__ W,
             const float* __restrict__ bias, float* __restrict__ out,
             int a_bstride, int ch_log2)
{
    __shared__ float As[BK][LDP];
    __shared__ float Ws[BK][LDP];

    const int tid   = threadIdx.x;
    const int m_blk = blockIdx.x * BM;
    const int n_blk = blockIdx.y * BN;

    const int tn = (tid & 15) * 4;
    const int tm = (tid >> 4) * 4;

    float acc[8][8];
    #pragma unroll
    for (int i = 0; i < 8; ++i)
        #pragma unroll
        for (int j = 0; j < 8; ++j) acc[i][j] = 0.f;

    const int lrow = tid >> 2;
    const int lkc  = (tid & 3) * 4;
    const int CHm1 = (1 << ch_log2) - 1;

    for (int k0 = 0; k0 < HID; k0 += BK) {
        #pragma unroll
        for (int p = 0; p < 2; ++p) {
            int row = p * 64 + lrow;
            int r   = m_blk + row;
            int b   = r >> ch_log2;
            int t   = r & CHm1;
            const float4 a = *(const float4*)(A + (size_t)b * a_bstride +
                                              (size_t)t * HID + k0 + lkc);
            As[lkc + 0][row] = a.x;
            As[lkc + 1][row] = a.y;
            As[lkc + 2][row] = a.z;
            As[lkc + 3][row] = a.w;

            int g = n_blk + row;
            const float4 w = *(const float4*)(W + (size_t)g * HID + k0 + lkc);
            Ws[lkc + 0][row] = w.x;
            Ws[lkc + 1][row] = w.y;
            Ws[lkc + 2][row] = w.z;
            Ws[lkc + 3][row] = w.w;
        }
        __syncthreads();

        #pragma unroll
        for (int kk = 0; kk < BK; ++kk) {
            float4 a0 = *(const float4*)&As[kk][tm];
            float4 a1 = *(const float4*)&As[kk][tm + 64];
            float4 b0 = *(const float4*)&Ws[kk][tn];
            float4 b1 = *(const float4*)&Ws[kk][tn + 64];
            float av[8] = {a0.x, a0.y, a0.z, a0.w, a1.x, a1.y, a1.z, a1.w};
            float bv[8] = {b0.x, b0.y, b0.z, b0.w, b1.x, b1.y, b1.z, b1.w};
            #pragma unroll
            for (int i = 0; i < 8; ++i)
                #pragma unroll
                for (int j = 0; j < 8; ++j)
                    acc[i][j] += av[i] * bv[j];
        }
        __syncthreads();
    }

    const float4 bias0 = *(const float4*)&bias[n_blk + tn];
    const float4 bias1 = *(const float4*)&bias[n_blk + tn + 64];
    #pragma unroll
    for (int i = 0; i < 8; ++i) {
        int m  = (i < 4) ? (tm + i) : (tm + 60 + i);
        int gm = m_blk + m;
        float* op = out + (size_t)gm * GATES + n_blk;
        float4 v0 = {acc[i][0] + bias0.x, acc[i][1] + bias0.y,
                     acc[i][2] + bias0.z, acc[i][3] + bias0.w};
        float4 v1 = {acc[i][4] + bias1.x, acc[i][5] + bias1.y,
                     acc[i][6] + bias1.z, acc[i][7] + bias1.w};
        *(float4*)(op + tn)      = v0;
        *(float4*)(op + tn + 64) = v1;
    }
}

// ---------------------------------------------------------------------------
// v16 = v15 + two contention fixes targeting the observed cycle inflation
// (2.05 -> ~3 us when gemm wgs co-reside):
//  (a) NON-TEMPORAL loads/stores for ALL gemm streaming traffic (A, W, xg
//      out). These have zero reuse outside the wg (LDS-staged), so `nt`
//      keeps the ~1MB of mailbox lines L2-resident -> publish->poll RT
//      stays at L2 latency instead of being evicted to HBM (~900cyc).
//  (b) s_setprio(1) on rec waves: gemm waves (prio 0) only win genuinely
//      idle issue slots; rec's latency-critical poll/reduce path goes first.
// Everything else identical to v15 (VGPR=64 verified, fusion correct).
// ---------------------------------------------------------------------------
#define MBSTRIDE ((size_t)BATCH * HID)   // ulongs per parity block

__device__ __forceinline__ float sigmoid_f(float x) {
    return 1.f / (1.f + __expf(-x));
}
__device__ __forceinline__ float tanh_f(float x) {
    return 1.f - 2.f / (1.f + __expf(2.f * x));
}

typedef float vfloat4 __attribute__((ext_vector_type(4)));

__device__ __forceinline__ float4 nt_load4(const float* p) {
    vfloat4 v = __builtin_nontemporal_load((const vfloat4*)p);
    float4 r; r.x = v.x; r.y = v.y; r.z = v.z; r.w = v.w;
    return r;
}
__device__ __forceinline__ void nt_store4(float* p, float4 a) {
    vfloat4 v; v.x = a.x; v.y = a.y; v.z = a.z; v.w = a.w;
    __builtin_nontemporal_store(v, (vfloat4*)p);
}

// 1024-thread GEMM tile (128x128, 4x4 micro), nt on all streaming accesses.
__device__ void gemm_path(const float* __restrict__ A, int a_bstride,
                          const float* __restrict__ W, const float* __restrict__ bias,
                          float* __restrict__ out, int mtile, int ntile,
                          int ch_log2, float* smem)
{
    float (*As)[LDP] = (float(*)[LDP])smem;
    float (*Ws)[LDP] = (float(*)[LDP])(smem + BK * LDP);

    const int tid   = threadIdx.x;
    const int m_blk = mtile * 128;
    const int n_blk = ntile * 128;
    const int tm = (tid >> 5) * 4;       // 0..124
    const int tn = (tid & 31) * 4;       // 0..124
    const int lrow = (tid & 511) >> 2;   // 0..127
    const int lkc  = (tid & 3) * 4;
    const int CHm1 = (1 << ch_log2) - 1;

    float acc[4][4];
    #pragma unroll
    for (int i = 0; i < 4; ++i)
        #pragma unroll
        for (int j = 0; j < 4; ++j) acc[i][j] = 0.f;

    for (int k0 = 0; k0 < HID; k0 += BK) {
        if (tid < 512) {
            int r = m_blk + lrow;
            int b = r >> ch_log2;
            int t = r & CHm1;
            const float4 a = nt_load4(A + (size_t)b * a_bstride +
                                      (size_t)t * HID + k0 + lkc);
            As[lkc + 0][lrow] = a.x;
            As[lkc + 1][lrow] = a.y;
            As[lkc + 2][lrow] = a.z;
            As[lkc + 3][lrow] = a.w;
        } else {
            int g = n_blk + lrow;
            const float4 w = nt_load4(W + (size_t)g * HID + k0 + lkc);
            Ws[lkc + 0][lrow] = w.x;
            Ws[lkc + 1][lrow] = w.y;
            Ws[lkc + 2][lrow] = w.z;
            Ws[lkc + 3][lrow] = w.w;
        }
        __syncthreads();

        #pragma unroll
        for (int kk = 0; kk < BK; ++kk) {
            float4 a4 = *(const float4*)&As[kk][tm];
            float4 b4 = *(const float4*)&Ws[kk][tn];
            float av[4] = {a4.x, a4.y, a4.z, a4.w};
            float bv[4] = {b4.x, b4.y, b4.z, b4.w};
            #pragma unroll
            for (int i = 0; i < 4; ++i)
                #pragma unroll
                for (int j = 0; j < 4; ++j)
                    acc[i][j] += av[i] * bv[j];
        }
        __syncthreads();
    }

    const float4 bi = *(const float4*)&bias[n_blk + tn];
    #pragma unroll
    for (int i = 0; i < 4; ++i) {
        int gm = m_blk + tm + i;
        float4 v = {acc[i][0] + bi.x, acc[i][1] + bi.y,
                    acc[i][2] + bi.z, acc[i][3] + bi.w};
        nt_store4(out + (size_t)gm * GATES + n_blk + tn, v);
    }
}

__global__ __launch_bounds__(1024, 4)
void fused_step(const float* __restrict__ xgA, const float* __restrict__ xgB,
                const float* __restrict__ w_hh, const float* __restrict__ b_hh,
                unsigned long long* mb1, unsigned long long* mb2,
                float* __restrict__ cs1, float* __restrict__ cs2,
                float* __restrict__ h1dst,
                int CH, int ch_log2, int gbaseA, int gbaseB, int doA, int doB,
                const float* __restrict__ gAsrc, int gAstride,
                const float* __restrict__ wA, const float* __restrict__ bA,
                float* __restrict__ gAdst, int doGA,
                const float* __restrict__ gBsrc, int gBstride,
                const float* __restrict__ wB, const float* __restrict__ bB,
                float* __restrict__ gBdst, int doGB)
{
    // union: rec uses 8960 floats (hsh 2x320 + part 2x4160); gemm uses 4224
    __shared__ __attribute__((aligned(16))) float smem[8960];

    const int bid = blockIdx.x;

    // =================== GEMM wgs (bid >= 256), prio 0 ===================
    if (bid >= 256) {
        const int MT  = (BATCH * CH) >> 7;   // M-tiles per gemm
        const int per = MT * (GATES / 128);
        int g = bid - 256;
        if (g < per) {
            if (!doGA) return;
            gemm_path(gAsrc, gAstride, wA, bA, gAdst, g >> 3, g & 7,
                      ch_log2, smem);
        } else {
            if (!doGB) return;
            g -= per;
            gemm_path(gBsrc, gBstride, wB, bB, gBdst, g >> 3, g & 7,
                      ch_log2, smem);
        }
        return;
    }

    // =================== rec wgs (bid < 256): v13 body, prio 1 ===========
    const int layer = bid >> 7;
    if (layer == 0 && !doA) return;
    if (layer == 1 && !doB) return;

    __builtin_amdgcn_s_setprio(1);   // rec waves win issue arbitration

    float* hsh0  = smem;                 // [320]: 16 chunks x 20
    float* hsh1  = smem + 320;
    float* part0 = smem + 640;           // [16][260]
    float* part1 = smem + 640 + 4160;

    const int lid = bid & 127;
    const int s   = lid & 3;             // slice: units [s*64, s*64+64)
    const int b0  = (lid >> 2) * 2;      // batches {b0, b0+1}
    const int tid = threadIdx.x;
    const int kc  = tid & 15;            // k-chunk of 16
    const int u   = tid >> 4;            // unit 0..63
    const int gu  = s * 64 + u;

    const float* xgL = layer ? xgB : xgA;
    const float* wL  = w_hh + (size_t)layer * GATES * HID;
    const float* bL  = b_hh + layer * GATES;
    unsigned long long* mbL = layer ? mb2 : mb1;
    float* csL = layer ? cs2 : cs1;
    const int gbase = layer ? gbaseB : gbaseA;

    // ---- one-time: 4 gate-rows x 16 weights into registers, laundered ----
    float4 wreg[4][4];
    #pragma unroll
    for (int j = 0; j < 4; ++j) {
        const float* wr = wL + (size_t)(j * 256 + gu) * HID + kc * 16;
        #pragma unroll
        for (int i = 0; i < 4; ++i) {
            float4 w = *(const float4*)(wr + 4 * i);
            asm volatile("" : "+v"(w.x), "+v"(w.y), "+v"(w.z), "+v"(w.w));
            wreg[j][i] = w;
        }
    }

    // ---- owner identity: wave0 -> batch b0, wave1 -> b0+1 ----
    const int u_o  = tid & 63;
    const int gu_o = s * 64 + u_o;
    const int b_o  = b0 + ((tid >> 6) & 1);   // valid for tid<128
    float c_u = 0.f;
    float bh[4] = {0.f, 0.f, 0.f, 0.f};
    float xv[4] = {0.f, 0.f, 0.f, 0.f};
    if (tid < 128) {
        c_u = csL[b_o * HID + gu_o];
        #pragma unroll
        for (int g = 0; g < 4; ++g) bh[g] = bL[g * 256 + gu_o];
    }

    // ---- poller identity: waves 12-15, slot pt in [0,256) ----
    const int pt = tid - 768;

    for (int t = 0; t < CH; ++t) {
        const int gt = gbase + t;
        const int pr = gt & 1;

        // ================= S1 =================
        if (tid >= 768) {
            const unsigned long long* slot =
                mbL + (size_t)pr * MBSTRIDE + b0 * HID + pt;
            unsigned long long w;
            do {
                w = __hip_atomic_load(slot, __ATOMIC_RELAXED,
                                      __HIP_MEMORY_SCOPE_AGENT);
            } while ((unsigned)(w >> 32) != (unsigned)gt);
            hsh0[(pt >> 4) * 20 + (pt & 15)] = __uint_as_float((unsigned)w);
        } else if (tid < 128) {
            if ((tid & 64) && t > 0) {
                // w1: finish b1 step t-1: reduce part1, update, publish gt
                float gx = 0.f, gy = 0.f, gz = 0.f, gw = 0.f;
                #pragma unroll
                for (int k = 0; k < 16; ++k) {
                    float4 pk = *(const float4*)&part1[k * 260 + 4 * u_o];
                    gx += pk.x; gy += pk.y; gz += pk.z; gw += pk.w;
                }
                float ig = sigmoid_f(gx + xv[0] + bh[0]);
                float fg = sigmoid_f(gy + xv[1] + bh[1]);
                float gv = tanh_f   (gz + xv[2] + bh[2]);
                float og = sigmoid_f(gw + xv[3] + bh[3]);
                c_u = fg * c_u + ig * gv;
                float h = og * tanh_f(c_u);
                __hip_atomic_store(
                    mbL + (size_t)(gt & 1) * MBSTRIDE + b_o * HID + gu_o,
                    ((unsigned long long)(unsigned)gt << 32) |
                        (unsigned long long)__float_as_uint(h),
                    __ATOMIC_RELAXED, __HIP_MEMORY_SCOPE_AGENT);
                if (layer == 0)
                    h1dst[((size_t)b_o * CH + (t - 1)) * HID + gu_o] = h;
            }
            const float* xp = xgL + ((size_t)b_o * CH + t) * GATES;
            #pragma unroll
            for (int g = 0; g < 4; ++g) xv[g] = xp[g * 256 + gu_o];
        }
        __syncthreads();   // barA: hsh0 ready; part1(t-1) consumed

        // ================= S2: matvec b0 -> part0 =================
        {
            const float4* hq = (const float4*)&hsh0[kc * 20];
            float4 h0 = hq[0], h1 = hq[1], h2 = hq[2], h3 = hq[3];
            float4 pv;
            float* pp = (float*)&pv;
            #pragma unroll
            for (int j = 0; j < 4; ++j) {
                float a = wreg[j][0].x * h0.x + wreg[j][0].y * h0.y
                        + wreg[j][0].z * h0.z + wreg[j][0].w * h0.w;
                a += wreg[j][1].x * h1.x + wreg[j][1].y * h1.y
                   + wreg[j][1].z * h1.z + wreg[j][1].w * h1.w;
                a += wreg[j][2].x * h2.x + wreg[j][2].y * h2.y
                   + wreg[j][2].z * h2.z + wreg[j][2].w * h2.w;
                a += wreg[j][3].x * h3.x + wreg[j][3].y * h3.y
                   + wreg[j][3].z * h3.z + wreg[j][3].w * h3.w;
                pp[j] = a;
            }
            *(float4*)&part0[kc * 260 + 4 * u] = pv;
        }
        __syncthreads();   // barB: part0 ready

        // ================= S3 =================
        if (tid < 64) {
            // w0: finish b0 step t: reduce part0, update, publish gt+1
            float gx = 0.f, gy = 0.f, gz = 0.f, gw = 0.f;
            #pragma unroll
            for (int k = 0; k < 16; ++k) {
                float4 pk = *(const float4*)&part0[k * 260 + 4 * u_o];
                gx += pk.x; gy += pk.y; gz += pk.z; gw += pk.w;
            }
            float ig = sigmoid_f(gx + xv[0] + bh[0]);
            float fg = sigmoid_f(gy + xv[1] + bh[1]);
            float gv = tanh_f   (gz + xv[2] + bh[2]);
            float og = sigmoid_f(gw + xv[3] + bh[3]);
            c_u = fg * c_u + ig * gv;
            float h = og * tanh_f(c_u);
            __hip_atomic_store(
                mbL + (size_t)((gt + 1) & 1) * MBSTRIDE + b_o * HID + gu_o,
                ((unsigned long long)(unsigned)(gt + 1) << 32) |
                    (unsigned long long)__float_as_uint(h),
                __ATOMIC_RELAXED, __HIP_MEMORY_SCOPE_AGENT);
            if (layer == 0)
                h1dst[((size_t)b_o * CH + t) * HID + gu_o] = h;
        } else if (tid >= 768) {
            const unsigned long long* slot =
                mbL + (size_t)pr * MBSTRIDE + (b0 + 1) * HID + pt;
            unsigned long long w;
            do {
                w = __hip_atomic_load(slot, __ATOMIC_RELAXED,
                                      __HIP_MEMORY_SCOPE_AGENT);
            } while ((unsigned)(w >> 32) != (unsigned)gt);
            hsh1[(pt >> 4) * 20 + (pt & 15)] = __uint_as_float((unsigned)w);
        }
        __syncthreads();   // barC: hsh1 ready; part0 consumed

        // ================= S4: matvec b1 -> part1 =================
        {
            const float4* hq = (const float4*)&hsh1[kc * 20];
            float4 h0 = hq[0], h1 = hq[1], h2 = hq[2], h3 = hq[3];
            float4 pv;
            float* pp = (float*)&pv;
            #pragma unroll
            for (int j = 0; j < 4; ++j) {
                float a = wreg[j][0].x * h0.x + wreg[j][0].y * h0.y
                        + wreg[j][0].z * h0.z + wreg[j][0].w * h0.w;
                a += wreg[j][1].x * h1.x + wreg[j][1].y * h1.y
                   + wreg[j][1].z * h1.z + wreg[j][1].w * h1.w;
                a += wreg[j][2].x * h2.x + wreg[j][2].y * h2.y
                   + wreg[j][2].z * h2.z + wreg[j][2].w * h2.w;
                a += wreg[j][3].x * h3.x + wreg[j][3].y * h3.y
                   + wreg[j][3].z * h3.z + wreg[j][3].w * h3.w;
                pp[j] = a;
            }
            *(float4*)&part1[kc * 260 + 4 * u] = pv;
        }
        __syncthreads();   // barD: part1 ready -> consumed next S1
    }

    // ---- epilogue: w1 finishes b1 step CH-1 (tag gbase+CH) ----
    if (tid >= 64 && tid < 128) {
        const int gt_e = gbase + CH;
        float gx = 0.f, gy = 0.f, gz = 0.f, gw = 0.f;
        #pragma unroll
        for (int k = 0; k < 16; ++k) {
            float4 pk = *(const float4*)&part1[k * 260 + 4 * u_o];
            gx += pk.x; gy += pk.y; gz += pk.z; gw += pk.w;
        }
        float ig = sigmoid_f(gx + xv[0] + bh[0]);
        float fg = sigmoid_f(gy + xv[1] + bh[1]);
        float gv = tanh_f   (gz + xv[2] + bh[2]);
        float og = sigmoid_f(gw + xv[3] + bh[3]);
        c_u = fg * c_u + ig * gv;
        float h = og * tanh_f(c_u);
        __hip_atomic_store(
            mbL + (size_t)(gt_e & 1) * MBSTRIDE + b_o * HID + gu_o,
            ((unsigned long long)(unsigned)gt_e << 32) |
                (unsigned long long)__float_as_uint(h),
            __ATOMIC_RELAXED, __HIP_MEMORY_SCOPE_AGENT);
        if (layer == 0)
            h1dst[((size_t)b_o * CH + (CH - 1)) * HID + gu_o] = h;
    }

    if (tid < 128) csL[b_o * HID + gu_o] = c_u;
}

// ---------------------------------------------------------------------------
__global__ void final_linear(const unsigned long long* __restrict__ hw,
                             const float* __restrict__ w_lin,
                             const float* __restrict__ b_lin,
                             float* __restrict__ out)
{
    int b = blockIdx.x;
    int l = threadIdx.x;
    float p = 0.f;
    #pragma unroll
    for (int j = 0; j < 4; ++j) {
        int u = l + j * 64;
        p += __uint_as_float((unsigned)hw[b * HID + u]) * w_lin[u];
    }
    #pragma unroll
    for (int off = 32; off > 0; off >>= 1) p += __shfl_down(p, off, 64);
    if (l == 0) out[b] = p + b_lin[0];
}

// ---------------------------------------------------------------------------
extern "C" void kernel_launch(void* const* d_in, const int* in_sizes, int n_in,
                              void* d_out, int out_size, void* d_ws, size_t ws_size,
                              hipStream_t stream)
{
    const float* input = (const float*)d_in[0];
    const float* w_ih  = (const float*)d_in[1];
    const float* w_hh  = (const float*)d_in[2];
    const float* b_ih  = (const float*)d_in[3];
    const float* b_hh  = (const float*)d_in[4];
    const float* w_lin = (const float*)d_in[5];
    const float* b_lin = (const float*)d_in[6];
    float* out = (float*)d_out;

    const size_t c_elems  = (size_t)BATCH * HID;
    const size_t mb_bytes = 2 * MBSTRIDE * sizeof(unsigned long long);
    char*  ws   = (char*)d_ws;
    float* cs1  = (float*)ws;
    float* cs2  = cs1 + c_elems;
    unsigned long long* mb1 = (unsigned long long*)(cs2 + c_elems);
    unsigned long long* mb2 = mb1 + 2 * MBSTRIDE;
    const size_t zero_bytes = 2 * c_elems * 4 + 2 * mb_bytes;
    float* big  = (float*)(ws + ((zero_bytes + 255) & ~(size_t)255));

    // lag-2 pipeline needs xg1[2], xg2[2], h1[2]
    int CH = 128;
    while (CH > 16) {
        size_t need = ((zero_bytes + 255) & ~(size_t)255)
                    + ((size_t)4 * BATCH * CH * GATES +
                       (size_t)2 * BATCH * CH * HID) * 4;
        if (need <= ws_size) break;
        CH >>= 1;
    }
    const int ch_log2 = __builtin_ctz((unsigned)CH);
    const size_t xg_sz = (size_t)BATCH * CH * GATES;
    const size_t h1_sz = (size_t)BATCH * CH * HID;

    float* xg1[2] = {big, big + xg_sz};
    float* xg2[2] = {big + 2 * xg_sz, big + 3 * xg_sz};
    float* h1p[2] = {big + 4 * xg_sz, big + 4 * xg_sz + h1_sz};

    hipMemsetAsync(ws, 0, zero_bytes, stream);

    const int NC = SEQ / CH;
    const int MT = (BATCH * CH) >> 7;           // gemm M-tiles
    const int GRID = 256 + 2 * MT * (GATES / 128);

    // prologue: xg1(0)
    dim3 gblk(MT, GATES / BN);
    xg_gemm<<<gblk, 256, 0, stream>>>(input, w_ih, b_ih, xg1[0],
                                      SEQ * HID, ch_log2);

    // fused pipeline: dispatch d = rec-A(d) + rec-B(d-2) + gemmA(d+1) + gemmB(d-1)
    for (int d = 0; d <= NC + 1; ++d) {
        const int doA  = (d < NC) ? 1 : 0;
        const int doB  = (d >= 2) ? 1 : 0;
        const int doGA = (d + 1 < NC) ? 1 : 0;
        const int doGB = (d >= 1 && d <= NC) ? 1 : 0;

        const float* gAsrc = doGA ? (input + (size_t)(d + 1) * CH * HID) : input;
        const float* gBsrc = h1p[(d - 1) & 1];

        fused_step<<<GRID, 1024, 0, stream>>>(
            xg1[d & 1], xg2[d & 1], w_hh, b_hh, mb1, mb2, cs1, cs2,
            h1p[d & 1], CH, ch_log2, d * CH, (d - 2) * CH, doA, doB,
            gAsrc, SEQ * HID, w_ih, b_ih, xg1[(d + 1) & 1], doGA,
            gBsrc, CH * HID, w_ih + (size_t)GATES * HID, b_ih + GATES,
            xg2[(d - 1) & 1], doGB);
    }

    // last h2 (step 2047, tag 2048) sits in mb2 parity-0 block
    final_linear<<<BATCH, 64, 0, stream>>>(mb2, w_lin, b_lin, out);
}

// Round 11
// 6097.671 us; speedup vs baseline: 1.1214x; 1.1214x over previous
//
#include <hip/hip_runtime.h>
#include <math.h>

#define HID   256
#define GATES 1024   // 4*HID
#define BATCH 64
#define SEQ   2048

// ---------------------------------------------------------------------------
// GEMM: out[r][g] = sum_k A_row(r)[k] * W[g][k] + bias[g]   (proven, 98 TF)
// ---------------------------------------------------------------------------
#define BM 128
#define BN 128
#define BK 16
#define LDP 132

__global__ __launch_bounds__(256, 2)
void xg_gemm(const float* __restrict__ A, const float* __restrict__ W,
             const float* __restrict__ bias, float* __restrict__ out,
             int a_bstride, int ch_log2)
{
    __shared__ float As[BK][LDP];
    __shared__ float Ws[BK][LDP];

    const int tid   = threadIdx.x;
    const int m_blk = blockIdx.x * BM;
    const int n_blk = blockIdx.y * BN;

    const int tn = (tid & 15) * 4;
    const int tm = (tid >> 4) * 4;

    float acc[8][8];
    #pragma unroll
    for (int i = 0; i < 8; ++i)
        #pragma unroll
        for (int j = 0; j < 8; ++j) acc[i][j] = 0.f;

    const int lrow = tid >> 2;
    const int lkc  = (tid & 3) * 4;
    const int CHm1 = (1 << ch_log2) - 1;

    for (int k0 = 0; k0 < HID; k0 += BK) {
        #pragma unroll
        for (int p = 0; p < 2; ++p) {
            int row = p * 64 + lrow;
            int r   = m_blk + row;
            int b   = r >> ch_log2;
            int t   = r & CHm1;
            const float4 a = *(const float4*)(A + (size_t)b * a_bstride +
                                              (size_t)t * HID + k0 + lkc);
            As[lkc + 0][row] = a.x;
            As[lkc + 1][row] = a.y;
            As[lkc + 2][row] = a.z;
            As[lkc + 3][row] = a.w;

            int g = n_blk + row;
            const float4 w = *(const float4*)(W + (size_t)g * HID + k0 + lkc);
            Ws[lkc + 0][row] = w.x;
            Ws[lkc + 1][row] = w.y;
            Ws[lkc + 2][row] = w.z;
            Ws[lkc + 3][row] = w.w;
        }
        __syncthreads();

        #pragma unroll
        for (int kk = 0; kk < BK; ++kk) {
            float4 a0 = *(const float4*)&As[kk][tm];
            float4 a1 = *(const float4*)&As[kk][tm + 64];
            float4 b0 = *(const float4*)&Ws[kk][tn];
            float4 b1 = *(const float4*)&Ws[kk][tn + 64];
            float av[8] = {a0.x, a0.y, a0.z, a0.w, a1.x, a1.y, a1.z, a1.w};
            float bv[8] = {b0.x, b0.y, b0.z, b0.w, b1.x, b1.y, b1.z, b1.w};
            #pragma unroll
            for (int i = 0; i < 8; ++i)
                #pragma unroll
                for (int j = 0; j < 8; ++j)
                    acc[i][j] += av[i] * bv[j];
        }
        __syncthreads();
    }

    const float4 bias0 = *(const float4*)&bias[n_blk + tn];
    const float4 bias1 = *(const float4*)&bias[n_blk + tn + 64];
    #pragma unroll
    for (int i = 0; i < 8; ++i) {
        int m  = (i < 4) ? (tm + i) : (tm + 60 + i);
        int gm = m_blk + m;
        float* op = out + (size_t)gm * GATES + n_blk;
        float4 v0 = {acc[i][0] + bias0.x, acc[i][1] + bias0.y,
                     acc[i][2] + bias0.z, acc[i][3] + bias0.w};
        float4 v1 = {acc[i][4] + bias1.x, acc[i][5] + bias1.y,
                     acc[i][6] + bias1.z, acc[i][7] + bias1.w};
        *(float4*)(op + tn)      = v0;
        *(float4*)(op + tn + 64) = v1;
    }
}

// ---------------------------------------------------------------------------
// Recurrence v11 (FINAL — best measured: 6085 us total, ~2.05 us/cycle).
// v10 + 2-phase batch pipelining (4 barriers/cycle).
//
// Cycle:
//   S1: w1-owner finishes b1(t-1) [reduce part1, publish]; pollers poll b0(t)
//   barA | S2: all matvec b0 -> part0 | barB
//   S3: w0-owner reduces part0, publishes b0(t); pollers poll b1(t)
//   barC | S4: all matvec b1 -> part1 | barD
//
// Race audit: part0 read in S3(t), next write S2(t+1) after barA(t+1). part1
// read in S1(t+1), next write S4(t+1) after barC(t+1). hsh0 written S1
// (pre-barA), read S2; next write after barD(t). hsh1 written S3, read S4;
// next write after barB(t+1).
//
// Session ledger (why nothing else is here):
//  - weights pinned in 64 regs/thread: streaming variants (v9) thrash HBM 8x
//  - LDS part reduce, NOT shfl butterflies: v12 = +37% cycle (VALU chains)
//  - XCD co-location of mailbox peers: v13 = neutral (RT is a device
//    coherence constant ~1.3us, placement-independent)
//  - GEMM-in-shadow fusion: v15/v16 = wash-to-regression (contention tax
//    ~0.65us/cycle x 2304 == GEMM serial time saved; nt/setprio worsen it)
//  - structural floor: weights (1MB/layer) can't fit per-CU -> h all-gather
//    across 4 slice-CUs forced -> 2304 sequential coherence RTs + ~0.7us
//    compute/sync each + 1.4ms VALU-bound fp32 GEMM (no fp32 MFMA on CDNA4)
// ---------------------------------------------------------------------------
#define MBSTRIDE ((size_t)BATCH * HID)   // ulongs per parity block

__device__ __forceinline__ float sigmoid_f(float x) {
    return 1.f / (1.f + __expf(-x));
}
__device__ __forceinline__ float tanh_f(float x) {
    return 1.f - 2.f / (1.f + __expf(2.f * x));
}

__global__ __launch_bounds__(1024, 4)
void lstm_rec_v11(const float* __restrict__ xg1, const float* __restrict__ xg2,
                  const float* __restrict__ w_hh, const float* __restrict__ b_hh,
                  unsigned long long* mb1, unsigned long long* mb2,
                  float* __restrict__ cs1, float* __restrict__ cs2,
                  float* __restrict__ h1ch,
                  int CH, int gbaseA, int gbaseB, int doA, int doB)
{
    // h(t-1) per phase: 16 chunks of 16 floats padded to 20
    __shared__ __attribute__((aligned(16))) float hsh[2][16 * 20];
    // partials double-buffered per phase: part[ph][kc][4u+j]
    __shared__ __attribute__((aligned(16))) float part[2][16][260];
    __shared__ float occ_pad[3328];

    const int bid   = blockIdx.x;
    const int layer = bid >> 7;
    if (layer == 0 && !doA) return;
    if (layer == 1 && !doB) return;

    // keep occ_pad alive: runtime-unprovable guard + volatile accesses
    if (gbaseA == 0x7fffffff) {
        volatile float* vp = occ_pad;
        vp[threadIdx.x] = (float)CH;
        cs1[0] = vp[threadIdx.x ^ 1];
    }

    const int lid = bid & 127;
    const int s   = lid & 3;             // slice: units [s*64, s*64+64)
    const int b0  = (lid >> 2) * 2;      // batches {b0, b0+1}
    const int tid = threadIdx.x;
    const int kc  = tid & 15;            // k-chunk of 16
    const int u   = tid >> 4;            // unit 0..63
    const int gu  = s * 64 + u;

    const float* xgL = layer ? xg2 : xg1;
    const float* wL  = w_hh + (size_t)layer * GATES * HID;
    const float* bL  = b_hh + layer * GATES;
    unsigned long long* mbL = layer ? mb2 : mb1;
    float* csL = layer ? cs2 : cs1;
    const int gbase = layer ? gbaseB : gbaseA;

    // ---- one-time: 4 gate-rows x 16 weights into registers, laundered ----
    float4 wreg[4][4];
    #pragma unroll
    for (int j = 0; j < 4; ++j) {
        const float* wr = wL + (size_t)(j * 256 + gu) * HID + kc * 16;
        #pragma unroll
        for (int i = 0; i < 4; ++i) {
            float4 w = *(const float4*)(wr + 4 * i);
            asm volatile("" : "+v"(w.x), "+v"(w.y), "+v"(w.z), "+v"(w.w));
            wreg[j][i] = w;
        }
    }

    // ---- owner identity: wave0 -> batch b0 (phase 0), wave1 -> b0+1 ----
    const int u_o  = tid & 63;
    const int gu_o = s * 64 + u_o;
    const int b_o  = b0 + ((tid >> 6) & 1);   // valid for tid<128
    float c_u = 0.f;
    float bh[4] = {0.f, 0.f, 0.f, 0.f};
    float xv[4] = {0.f, 0.f, 0.f, 0.f};
    if (tid < 128) {
        c_u = csL[b_o * HID + gu_o];
        #pragma unroll
        for (int g = 0; g < 4; ++g) bh[g] = bL[g * 256 + gu_o];
    }

    // ---- poller identity: waves 12-15, slot pt in [0,256) ----
    const int pt = tid - 768;

    for (int t = 0; t < CH; ++t) {
        const int gt = gbase + t;
        const int pr = gt & 1;

        // ================= S1 =================
        if (tid >= 768) {
            // poll b0 h(t-1), tag gt (published by w0 in S3 of prev cycle)
            const unsigned long long* slot =
                mbL + (size_t)pr * MBSTRIDE + b0 * HID + pt;
            unsigned long long w;
            do {
                w = __hip_atomic_load(slot, __ATOMIC_RELAXED,
                                      __HIP_MEMORY_SCOPE_AGENT);
            } while ((unsigned)(w >> 32) != (unsigned)gt);
            hsh[0][(pt >> 4) * 20 + (pt & 15)] = __uint_as_float((unsigned)w);
        } else if (tid < 128) {
            if ((tid & 64) && t > 0) {
                // w1: finish b1 step t-1: reduce part1, update, publish tag gt
                float gx = 0.f, gy = 0.f, gz = 0.f, gw = 0.f;
                #pragma unroll
                for (int k = 0; k < 16; ++k) {
                    float4 pk = *(const float4*)&part[1][k][4 * u_o];
                    gx += pk.x; gy += pk.y; gz += pk.z; gw += pk.w;
                }
                float ig = sigmoid_f(gx + xv[0] + bh[0]);
                float fg = sigmoid_f(gy + xv[1] + bh[1]);
                float gv = tanh_f   (gz + xv[2] + bh[2]);
                float og = sigmoid_f(gw + xv[3] + bh[3]);
                c_u = fg * c_u + ig * gv;
                float h = og * tanh_f(c_u);
                __hip_atomic_store(
                    mbL + (size_t)(gt & 1) * MBSTRIDE + b_o * HID + gu_o,
                    ((unsigned long long)(unsigned)gt << 32) |
                        (unsigned long long)__float_as_uint(h),
                    __ATOMIC_RELAXED, __HIP_MEMORY_SCOPE_AGENT);
                if (layer == 0)
                    h1ch[((size_t)b_o * CH + (t - 1)) * HID + gu_o] = h;
            }
            // owners (both waves): prefetch xv(t) for own batch
            const float* xp = xgL + ((size_t)b_o * CH + t) * GATES;
            #pragma unroll
            for (int g = 0; g < 4; ++g) xv[g] = xp[g * 256 + gu_o];
        }
        __syncthreads();   // barA: hsh0 ready; part1(t-1) consumed

        // ================= S2: matvec b0 -> part0 =================
        {
            const float4* hq = (const float4*)&hsh[0][kc * 20];
            float4 h0 = hq[0], h1 = hq[1], h2 = hq[2], h3 = hq[3];
            float4 pv;
            float* pp = (float*)&pv;
            #pragma unroll
            for (int j = 0; j < 4; ++j) {
                float a = wreg[j][0].x * h0.x + wreg[j][0].y * h0.y
                        + wreg[j][0].z * h0.z + wreg[j][0].w * h0.w;
                a += wreg[j][1].x * h1.x + wreg[j][1].y * h1.y
                   + wreg[j][1].z * h1.z + wreg[j][1].w * h1.w;
                a += wreg[j][2].x * h2.x + wreg[j][2].y * h2.y
                   + wreg[j][2].z * h2.z + wreg[j][2].w * h2.w;
                a += wreg[j][3].x * h3.x + wreg[j][3].y * h3.y
                   + wreg[j][3].z * h3.z + wreg[j][3].w * h3.w;
                pp[j] = a;
            }
            *(float4*)&part[0][kc][4 * u] = pv;
        }
        __syncthreads();   // barB: part0 ready

        // ================= S3 =================
        if (tid < 64) {
            // w0: finish b0 step t: reduce part0, update, publish tag gt+1
            float gx = 0.f, gy = 0.f, gz = 0.f, gw = 0.f;
            #pragma unroll
            for (int k = 0; k < 16; ++k) {
                float4 pk = *(const float4*)&part[0][k][4 * u_o];
                gx += pk.x; gy += pk.y; gz += pk.z; gw += pk.w;
            }
            float ig = sigmoid_f(gx + xv[0] + bh[0]);
            float fg = sigmoid_f(gy + xv[1] + bh[1]);
            float gv = tanh_f   (gz + xv[2] + bh[2]);
            float og = sigmoid_f(gw + xv[3] + bh[3]);
            c_u = fg * c_u + ig * gv;
            float h = og * tanh_f(c_u);
            __hip_atomic_store(
                mbL + (size_t)((gt + 1) & 1) * MBSTRIDE + b_o * HID + gu_o,
                ((unsigned long long)(unsigned)(gt + 1) << 32) |
                    (unsigned long long)__float_as_uint(h),
                __ATOMIC_RELAXED, __HIP_MEMORY_SCOPE_AGENT);
            if (layer == 0)
                h1ch[((size_t)b_o * CH + t) * HID + gu_o] = h;
        } else if (tid >= 768) {
            // poll b1 h(t-1), tag gt (published by w1 in S1 of THIS cycle)
            const unsigned long long* slot =
                mbL + (size_t)pr * MBSTRIDE + (b0 + 1) * HID + pt;
            unsigned long long w;
            do {
                w = __hip_atomic_load(slot, __ATOMIC_RELAXED,
                                      __HIP_MEMORY_SCOPE_AGENT);
            } while ((unsigned)(w >> 32) != (unsigned)gt);
            hsh[1][(pt >> 4) * 20 + (pt & 15)] = __uint_as_float((unsigned)w);
        }
        __syncthreads();   // barC: hsh1 ready; part0 consumed

        // ================= S4: matvec b1 -> part1 =================
        {
            const float4* hq = (const float4*)&hsh[1][kc * 20];
            float4 h0 = hq[0], h1 = hq[1], h2 = hq[2], h3 = hq[3];
            float4 pv;
            float* pp = (float*)&pv;
            #pragma unroll
            for (int j = 0; j < 4; ++j) {
                float a = wreg[j][0].x * h0.x + wreg[j][0].y * h0.y
                        + wreg[j][0].z * h0.z + wreg[j][0].w * h0.w;
                a += wreg[j][1].x * h1.x + wreg[j][1].y * h1.y
                   + wreg[j][1].z * h1.z + wreg[j][1].w * h1.w;
                a += wreg[j][2].x * h2.x + wreg[j][2].y * h2.y
                   + wreg[j][2].z * h2.z + wreg[j][2].w * h2.w;
                a += wreg[j][3].x * h3.x + wreg[j][3].y * h3.y
                   + wreg[j][3].z * h3.z + wreg[j][3].w * h3.w;
                pp[j] = a;
            }
            *(float4*)&part[1][kc][4 * u] = pv;
        }
        __syncthreads();   // barD: part1 ready -> consumed next S1
    }

    // ---- epilogue: w1 finishes b1 step CH-1 (tag gbase+CH) ----
    if (tid >= 64 && tid < 128) {
        const int gt_e = gbase + CH;
        float gx = 0.f, gy = 0.f, gz = 0.f, gw = 0.f;
        #pragma unroll
        for (int k = 0; k < 16; ++k) {
            float4 pk = *(const float4*)&part[1][k][4 * u_o];
            gx += pk.x; gy += pk.y; gz += pk.z; gw += pk.w;
        }
        float ig = sigmoid_f(gx + xv[0] + bh[0]);
        float fg = sigmoid_f(gy + xv[1] + bh[1]);
        float gv = tanh_f   (gz + xv[2] + bh[2]);
        float og = sigmoid_f(gw + xv[3] + bh[3]);
        c_u = fg * c_u + ig * gv;
        float h = og * tanh_f(c_u);
        __hip_atomic_store(
            mbL + (size_t)(gt_e & 1) * MBSTRIDE + b_o * HID + gu_o,
            ((unsigned long long)(unsigned)gt_e << 32) |
                (unsigned long long)__float_as_uint(h),
            __ATOMIC_RELAXED, __HIP_MEMORY_SCOPE_AGENT);
        if (layer == 0)
            h1ch[((size_t)b_o * CH + (CH - 1)) * HID + gu_o] = h;
    }

    if (tid < 128) csL[b_o * HID + gu_o] = c_u;
}

// ---------------------------------------------------------------------------
__global__ void final_linear(const unsigned long long* __restrict__ hw,
                             const float* __restrict__ w_lin,
                             const float* __restrict__ b_lin,
                             float* __restrict__ out)
{
    int b = blockIdx.x;
    int l = threadIdx.x;
    float p = 0.f;
    #pragma unroll
    for (int j = 0; j < 4; ++j) {
        int u = l + j * 64;
        p += __uint_as_float((unsigned)hw[b * HID + u]) * w_lin[u];
    }
    #pragma unroll
    for (int off = 32; off > 0; off >>= 1) p += __shfl_down(p, off, 64);
    if (l == 0) out[b] = p + b_lin[0];
}

// ---------------------------------------------------------------------------
extern "C" void kernel_launch(void* const* d_in, const int* in_sizes, int n_in,
                              void* d_out, int out_size, void* d_ws, size_t ws_size,
                              hipStream_t stream)
{
    const float* input = (const float*)d_in[0];
    const float* w_ih  = (const float*)d_in[1];
    const float* w_hh  = (const float*)d_in[2];
    const float* b_ih  = (const float*)d_in[3];
    const float* b_hh  = (const float*)d_in[4];
    const float* w_lin = (const float*)d_in[5];
    const float* b_lin = (const float*)d_in[6];
    float* out = (float*)d_out;

    const size_t c_elems  = (size_t)BATCH * HID;
    const size_t mb_bytes = 2 * MBSTRIDE * sizeof(unsigned long long);
    char*  ws   = (char*)d_ws;
    float* cs1  = (float*)ws;
    float* cs2  = cs1 + c_elems;
    unsigned long long* mb1 = (unsigned long long*)(cs2 + c_elems);
    unsigned long long* mb2 = mb1 + 2 * MBSTRIDE;
    const size_t zero_bytes = 2 * c_elems * 4 + 2 * mb_bytes;
    float* big  = (float*)(ws + ((zero_bytes + 255) & ~(size_t)255));

    int CH = 256;   // fit-checked; falls back if ws_size is smaller
    while (CH > 16) {
        size_t need = ((zero_bytes + 255) & ~(size_t)255)
                    + ((size_t)2 * BATCH * CH * GATES + (size_t)BATCH * CH * HID) * 4;
        if (need <= ws_size) break;
        CH >>= 1;
    }
    const int ch_log2 = __builtin_ctz((unsigned)CH);

    float* xg1  = big;
    float* xg2  = xg1 + (size_t)BATCH * CH * GATES;
    float* h1ch = xg2 + (size_t)BATCH * CH * GATES;

    hipMemsetAsync(ws, 0, zero_bytes, stream);

    const int NC = SEQ / CH;
    dim3 gblk(BATCH * CH / BM, GATES / BN);

    // chunk-lag pipeline: dispatch c runs layer-1 on chunk c (wgs 0..127)
    // and layer-2 on chunk c-1 (wgs 128..255) concurrently; GEMM2(c-1)
    // consumes h1ch written by the previous rec dispatch.
    for (int c = 0; c <= NC; ++c) {
        if (c < NC)
            xg_gemm<<<gblk, 256, 0, stream>>>(input + (size_t)c * CH * HID, w_ih,
                                              b_ih, xg1, SEQ * HID, ch_log2);
        if (c >= 1)
            xg_gemm<<<gblk, 256, 0, stream>>>(h1ch, w_ih + (size_t)GATES * HID,
                                              b_ih + GATES, xg2, CH * HID, ch_log2);
        lstm_rec_v11<<<256, 1024, 0, stream>>>(xg1, xg2, w_hh, b_hh, mb1, mb2,
                                               cs1, cs2, h1ch, CH,
                                               c * CH, (c - 1) * CH,
                                               (c < NC) ? 1 : 0, (c >= 1) ? 1 : 0);
    }

    // last h2 (step 2047, tag 2048) sits in mb2 parity-0 block
    final_linear<<<BATCH, 64, 0, stream>>>(mb2, w_lin, b_lin, out);
}